// Round 7
// baseline (244.125 us; speedup 1.0000x reference)
//
#include <hip/hip_runtime.h>
#include <hip/hip_bf16.h>

#define B_    8
#define N_    2048
#define FIN_  128
#define FOUT_ 64
#define ALPHA_ 0.2f
#define LN_EPS_ 1e-5f

typedef __attribute__((ext_vector_type(8))) short short8;
typedef __attribute__((ext_vector_type(4))) float f32x4;

__device__ __forceinline__ short f2bf(float f) {
    __hip_bfloat16 h = __float2bfloat16(f);          // RNE
    return *reinterpret_cast<short*>(&h);
}
__device__ __forceinline__ float bf2f(short s) {
    return __uint_as_float(((unsigned)(unsigned short)s) << 16);
}

// ============ kernel P: pack adj (int32 0/1, 134 MB) -> bitmask (4.2 MB) ============
// 4096 blocks x 256 thr; thread t packs 32 consecutive ints into one word.
// bit k of word w == (adj[w*32+k] > 0). Pure HBM stream (~22 us).
__global__ __launch_bounds__(256) void k_pack(
    const int* __restrict__ adj, unsigned* __restrict__ mask)
{
    const size_t base = ((size_t)blockIdx.x * 256 + threadIdx.x) * 32;
    unsigned m = 0;
    #pragma unroll
    for (int c = 0; c < 8; ++c) {
        int4 v = *(const int4*)&adj[base + c * 4];
        m |= (v.x > 0 ? 1u : 0u) << (c * 4 + 0);
        m |= (v.y > 0 ? 1u : 0u) << (c * 4 + 1);
        m |= (v.z > 0 ? 1u : 0u) << (c * 4 + 2);
        m |= (v.w > 0 ? 1u : 0u) << (c * 4 + 3);
    }
    mask[base >> 5] = m;
}

// ============ kernel 0: precompute W bf16 B-fragments + Wa1/Wa2 (1 block) ============
__global__ __launch_bounds__(256) void k_prep(
    const float* __restrict__ W, const float* __restrict__ a,
    short* __restrict__ Wbf, float* __restrict__ Wa1g, float* __restrict__ Wa2g)
{
    const int t = threadIdx.x;
    #pragma unroll
    for (int c = 0; c < 4; ++c) {
        int g = t + 256 * c;
        int u = g >> 6, ln = g & 63;
        int ks = u >> 2, nt = u & 3;
        int n  = nt * 16 + (ln & 15);
        int k0 = ks * 32 + (ln >> 4) * 8;
        short8 v;
        #pragma unroll
        for (int jj = 0; jj < 8; ++jj) v[jj] = f2bf(W[(k0 + jj) * FOUT_ + n]);
        *(short8*)&Wbf[g * 8] = v;
    }
    if (t < FIN_) {
        float a1 = 0.f, a2 = 0.f;
        #pragma unroll
        for (int n = 0; n < FOUT_; n += 4) {
            float4 wv  = *(const float4*)&W[t * FOUT_ + n];
            float4 av1 = *(const float4*)&a[n];
            float4 av2 = *(const float4*)&a[FOUT_ + n];
            a1 += wv.x * av1.x + wv.y * av1.y + wv.z * av1.z + wv.w * av1.w;
            a2 += wv.x * av2.x + wv.y * av2.y + wv.z * av2.z + wv.w * av2.w;
        }
        Wa1g[t] = a1; Wa2g[t] = a2;
    }
}

// ============ kernel 1: h = x@W (bf16 MFMA) -> h_T bf16; s1, s2 ============
// 512 blocks x 256 thr; block = 32 rows; wave: M-tile mt=wave&1, N-tiles {nt0,nt0+1}.
__global__ __launch_bounds__(256) void k_proj(
    const float* __restrict__ x,
    const short* __restrict__ Wbf,          // precomputed B-frags (L2-resident)
    const float* __restrict__ Wa1g, const float* __restrict__ Wa2g,
    unsigned short* __restrict__ hT,        // (B*64, 2048) bf16 bits: h_T[b][o][j]
    float* __restrict__ s1, float* __restrict__ s2)
{
    __shared__ float Wa1l[FIN_], Wa2l[FIN_];
    const int t = threadIdx.x;
    const int row0 = blockIdx.x * 32;
    const int b   = row0 >> 11;
    const int ib0 = row0 & (N_ - 1);

    if (t < FIN_) { Wa1l[t] = Wa1g[t]; Wa2l[t] = Wa2g[t]; }
    __syncthreads();

    const int wave = t >> 6, lane = t & 63;
    const int m = lane & 15, quad = lane >> 4;
    const int mt = wave & 1, nt0 = (wave >> 1) * 2;
    const int row = row0 + mt * 16 + m;

    short8 fa[4];
    float s1p = 0.f, s2p = 0.f;
    #pragma unroll
    for (int ks = 0; ks < 4; ++ks) {
        int k0 = ks * 32 + quad * 8;
        float4 x0 = *(const float4*)&x[(size_t)row * FIN_ + k0];
        float4 x1 = *(const float4*)&x[(size_t)row * FIN_ + k0 + 4];
        float xs[8] = {x0.x, x0.y, x0.z, x0.w, x1.x, x1.y, x1.z, x1.w};
        short8 v;
        #pragma unroll
        for (int jj = 0; jj < 8; ++jj) {
            v[jj] = f2bf(xs[jj]);
            s1p += xs[jj] * Wa1l[k0 + jj];
            s2p += xs[jj] * Wa2l[k0 + jj];
        }
        fa[ks] = v;
    }
    s1p += __shfl_xor(s1p, 16); s1p += __shfl_xor(s1p, 32);
    s2p += __shfl_xor(s2p, 16); s2p += __shfl_xor(s2p, 32);
    if (wave < 2 && lane < 16) {            // wave 0 -> mt 0 rows, wave 1 -> mt 1 rows
        s1[row0 + wave * 16 + lane] = s1p;
        s2[row0 + wave * 16 + lane] = s2p;
    }

    f32x4 acc[2];
    acc[0] = (f32x4){0.f, 0.f, 0.f, 0.f};
    acc[1] = (f32x4){0.f, 0.f, 0.f, 0.f};
    #pragma unroll
    for (int ks = 0; ks < 4; ++ks) {
        #pragma unroll
        for (int q = 0; q < 2; ++q) {
            short8 fb = *(const short8*)&Wbf[((ks * 4 + nt0 + q) * 64 + lane) * 8];
            acc[q] = __builtin_amdgcn_mfma_f32_16x16x32_bf16(fa[ks], fb, acc[q], 0, 0, 0);
        }
    }
    #pragma unroll
    for (int q = 0; q < 2; ++q) {
        int o  = (nt0 + q) * 16 + m;
        int ib = ib0 + mt * 16 + quad * 4;
        ushort4 hv;
        hv.x = (unsigned short)f2bf(acc[q][0]);
        hv.y = (unsigned short)f2bf(acc[q][1]);
        hv.z = (unsigned short)f2bf(acc[q][2]);
        hv.w = (unsigned short)f2bf(acc[q][3]);
        *(ushort4*)&hT[(size_t)(b * 64 + o) * N_ + ib] = hv;
    }
}

// ============ kernel 2: masked softmax attention + MFMA PV + LN + ELU ============
// grid = B*(N/16) = 1024 blocks x 256 thr; ~33 KB LDS -> 4 blocks/CU.
// Hot loop has ZERO global loads except the Hb stage (overlapped with exp-phase):
// adj mask + s2 + score params are all LDS-resident.
__global__ __launch_bounds__(256) void k_attn(
    const unsigned* __restrict__ maskg,       // packed adj bits
    const unsigned short* __restrict__ hT,
    const float* __restrict__ s1g, const float* __restrict__ s2g,
    const float* __restrict__ gamma, const float* __restrict__ beta,
    float* __restrict__ out)
{
    __shared__ short Hb[16 * 64 * 8];          // 16 KB: h B-frags
    __shared__ __align__(16) char pool[4096];  // Wf (4 KB) aliased with hp (4 KB)
    __shared__ float s2l[N_];                  // 8 KB: full-batch s2
    __shared__ int maskL[16 * 68];             // 4.25 KB, stride 68 (16B-aligned, 2-way banks)
    __shared__ float s1l[16], ml[16];
    __shared__ float lp[4][16];
    __shared__ float red[4];
    short* Wf = (short*)pool;                  // [4*64*8] w A-frags
    float* hp = (float*)pool;                  // [16*64] epilogue h'

    const int t = threadIdx.x;
    const int wave = t >> 6, lane = t & 63;
    const int i_ = lane & 15, quad = lane >> 4;
    const int b  = blockIdx.x >> 7;
    const int i0 = (blockIdx.x & 127) * 16;
    const size_t sbase  = (size_t)b * N_;
    const size_t hTbase = (size_t)b * 64 * N_;

    // stage mask rows i0..i0+15 (16 x 64 words), one int4 per thread
    {
        int w4 = t * 4;                         // 1024 words total
        int r = w4 >> 6, c = w4 & 63;
        int4 mv = *(const int4*)&maskg[(sbase + i0 + r) * (N_ / 32) + c];
        *(int4*)&maskL[r * 68 + c] = mv;
    }

    // stage full s2 (2048 f32) + per-batch max
    float4 v0 = *(const float4*)&s2g[sbase + 4 * t];
    float4 v1 = *(const float4*)&s2g[sbase + 4 * (t + 256)];
    *(float4*)&s2l[4 * t] = v0;
    *(float4*)&s2l[4 * (t + 256)] = v1;
    float mx = fmaxf(fmaxf(fmaxf(v0.x, v0.y), fmaxf(v0.z, v0.w)),
                     fmaxf(fmaxf(v1.x, v1.y), fmaxf(v1.z, v1.w)));
    #pragma unroll
    for (int d = 32; d; d >>= 1) mx = fmaxf(mx, __shfl_xor(mx, d));
    if (lane == 0) red[wave] = mx;
    __syncthreads();
    {
        float smax = fmaxf(fmaxf(red[0], red[1]), fmaxf(red[2], red[3]));
        if (t < 16) {
            float s1v = s1g[sbase + i0 + t];
            s1l[t] = s1v;
            float v = s1v + smax;
            ml[t] = fmaxf(v, ALPHA_ * v);       // valid upper bound (lrelu monotone)
        }
    }
    __syncthreads();   // s1l/ml visible to all waves before tile 0 (R6 bug: missing)

    const int jr = wave * 32 + quad * 8;        // this thread's j-slice within a tile
    f32x4 acc = (f32x4){0.f, 0.f, 0.f, 0.f};
    float lpart = 0.f;

    for (int tile = 0; tile < 16; ++tile) {
        const int j0 = tile * 128;
        if (tile) __syncthreads();              // PV done with prev Hb/Wf

        // issue Hb global loads (consumed after w-phase)
        short8 hv[4];
        #pragma unroll
        for (int c = 0; c < 4; ++c) {
            int u  = c * 4 + wave;              // frag-set; wave-uniform
            int ks = u >> 2, nt = u & 3;
            int o  = nt * 16 + i_;
            int j2 = ks * 32 + quad * 8;
            hv[c] = *(const short8*)&hT[hTbase + (size_t)o * N_ + j0 + j2];
        }

        // w-phase: mask bits + s2 from LDS, no global traffic
        {
            unsigned bits = ((unsigned)maskL[i_ * 68 + tile * 4 + wave]) >> (quad * 8);
            float s1v = s1l[i_], mv = ml[i_];
            float sum = 0.f;
            short8 wv;
            #pragma unroll
            for (int jj = 0; jj < 8; ++jj) {
                float ev = s1v + s2l[j0 + jr + jj];
                ev = fmaxf(ev, ALPHA_ * ev);
                float w = ((bits >> jj) & 1) ? __expf(ev - mv) : 0.f;
                short ws = f2bf(w);
                wv[jj] = ws;
                sum += bf2f(ws);                // l consistent with bf16-rounded numerator
            }
            *(short8*)&Wf[t * 8] = wv;
            lpart += sum;
        }

        // write Hb (compiler waits vmcnt here, after the exp work)
        #pragma unroll
        for (int c = 0; c < 4; ++c)
            *(short8*)&Hb[((c * 4 + wave) * 64 + lane) * 8] = hv[c];

        __syncthreads();                        // Hb + Wf visible

        // PV: wave owns N-tile nt=wave; 4 MFMA
        #pragma unroll
        for (int ks = 0; ks < 4; ++ks) {
            short8 fa = *(short8*)&Wf[(ks * 64 + lane) * 8];
            short8 fb = *(short8*)&Hb[((ks * 4 + wave) * 64 + lane) * 8];
            acc = __builtin_amdgcn_mfma_f32_16x16x32_bf16(fa, fb, acc, 0, 0, 0);
        }
    }

    // l: reduce per-thread partials over quads, combine 4 k-slices
    lpart += __shfl_xor(lpart, 16);
    lpart += __shfl_xor(lpart, 32);
    if (lane < 16) lp[wave][lane] = lpart;
    __syncthreads();                            // also: last PV reads done before hp aliases Wf

    {
        int col = wave * 16 + i_;               // = o
        #pragma unroll
        for (int reg = 0; reg < 4; ++reg) {
            int r = quad * 4 + reg;             // = i
            float l = lp[0][r] + lp[1][r] + lp[2][r] + lp[3][r];
            hp[r * 64 + col] = acc[reg] / l;
        }
    }
    __syncthreads();

    {
        int o = lane;
        float g  = gamma[o];
        float be = beta[o];
        #pragma unroll
        for (int rr = 0; rr < 4; ++rr) {
            int i = wave * 4 + rr;
            float v = hp[i * 64 + o];
            float mu = v;
            #pragma unroll
            for (int d = 32; d; d >>= 1) mu += __shfl_xor(mu, d);
            mu *= (1.f / 64.f);
            float dv = v - mu;
            float var = dv * dv;
            #pragma unroll
            for (int d = 32; d; d >>= 1) var += __shfl_xor(var, d);
            var *= (1.f / 64.f);
            float y = dv * rsqrtf(var + LN_EPS_) * g + be;
            out[(sbase + i0 + i) * FOUT_ + o] = y > 0.f ? y : __expf(y) - 1.f;
        }
    }
}

extern "C" void kernel_launch(void* const* d_in, const int* in_sizes, int n_in,
                              void* d_out, int out_size, void* d_ws, size_t ws_size,
                              hipStream_t stream) {
    const float* x     = (const float*)d_in[0];
    const int*   adj   = (const int*)d_in[1];
    const float* W     = (const float*)d_in[2];
    const float* a     = (const float*)d_in[3];
    const float* gamma = (const float*)d_in[4];
    const float* beta  = (const float*)d_in[5];
    float* out = (float*)d_out;

    char* ws = (char*)d_ws;
    unsigned short* hT = (unsigned short*)ws;                      // 2 MB
    float* s1   = (float*)(ws + (size_t)B_ * 64 * N_ * 2);         // 64 KB
    float* s2   = s1 + (size_t)B_ * N_;                            // 64 KB
    short* Wbf  = (short*)(s2 + (size_t)B_ * N_);                  // 16 KB
    float* Wa1g = (float*)(Wbf + 16 * 64 * 8);                     // 512 B
    float* Wa2g = Wa1g + FIN_;                                     // 512 B
    unsigned* maskg = (unsigned*)(ws + (4 << 20));                 // 4.2 MB at +4 MB

    k_pack<<<4096, 256, 0, stream>>>(adj, maskg);
    k_prep<<<1, 256, 0, stream>>>(W, a, Wbf, Wa1g, Wa2g);
    k_proj<<<512, 256, 0, stream>>>(x, Wbf, Wa1g, Wa2g, hT, s1, s2);
    k_attn<<<B_ * (N_ / 16), 256, 0, stream>>>(maskg, hT, s1, s2, gamma, beta, out);
}

// Round 8
// 226.277 us; speedup vs baseline: 1.0789x; 1.0789x over previous
//
#include <hip/hip_runtime.h>
#include <hip/hip_bf16.h>

#define B_    8
#define N_    2048
#define FIN_  128
#define FOUT_ 64
#define ALPHA_ 0.2f
#define LN_EPS_ 1e-5f

typedef __attribute__((ext_vector_type(8))) short short8;
typedef __attribute__((ext_vector_type(4))) float f32x4;

__device__ __forceinline__ short f2bf(float f) {
    __hip_bfloat16 h = __float2bfloat16(f);          // RNE
    return *reinterpret_cast<short*>(&h);
}
__device__ __forceinline__ float bf2f(short s) {
    return __uint_as_float(((unsigned)(unsigned short)s) << 16);
}

// ============ kernel 1: h = x@W (bf16 MFMA) -> h_T bf16; s1, s2 (prep folded in) ============
// 512 blocks x 256 thr; block = 32 rows; wave: M-tile mt=wave&1, N-tiles {nt0,nt0+1}.
__global__ __launch_bounds__(256) void k_proj(
    const float* __restrict__ x,    // (B*N, 128)
    const float* __restrict__ W,    // (128, 64)  L2-resident after first touch
    const float* __restrict__ a,    // (128,)
    unsigned short* __restrict__ hT,// (B*64, 2048) bf16 bits: h_T[b][o][j]
    float* __restrict__ s1, float* __restrict__ s2)
{
    __shared__ short Wb[16 * 64 * 8];     // 16 KB: W B-frags, set u = ks*4+nt
    __shared__ float Wa1l[FIN_], Wa2l[FIN_];
    const int t = threadIdx.x;
    const int row0 = blockIdx.x * 32;
    const int b   = row0 >> 11;
    const int ib0 = row0 & (N_ - 1);

    // build W B-frags in LDS: Wb[(ks*4+nt)*64+ln] <- W[ks*32+(ln>>4)*8+jj][nt*16+(ln&15)]
    #pragma unroll
    for (int c = 0; c < 4; ++c) {
        int g = t + 256 * c;
        int u = g >> 6, ln = g & 63;
        int ks = u >> 2, nt = u & 3;
        int n  = nt * 16 + (ln & 15);
        int k0 = ks * 32 + (ln >> 4) * 8;
        short8 v;
        #pragma unroll
        for (int jj = 0; jj < 8; ++jj) v[jj] = f2bf(W[(k0 + jj) * FOUT_ + n]);
        *(short8*)&Wb[g * 8] = v;
    }
    // Wa1 = W@a1, Wa2 = W@a2
    if (t < FIN_) {
        float a1 = 0.f, a2 = 0.f;
        #pragma unroll
        for (int n = 0; n < FOUT_; n += 4) {
            float4 wv  = *(const float4*)&W[t * FOUT_ + n];
            float4 av1 = *(const float4*)&a[n];
            float4 av2 = *(const float4*)&a[FOUT_ + n];
            a1 += wv.x * av1.x + wv.y * av1.y + wv.z * av1.z + wv.w * av1.w;
            a2 += wv.x * av2.x + wv.y * av2.y + wv.z * av2.z + wv.w * av2.w;
        }
        Wa1l[t] = a1; Wa2l[t] = a2;
    }
    __syncthreads();

    const int wave = t >> 6, lane = t & 63;
    const int m = lane & 15, quad = lane >> 4;
    const int mt = wave & 1, nt0 = (wave >> 1) * 2;
    const int row = row0 + mt * 16 + m;

    short8 fa[4];
    float s1p = 0.f, s2p = 0.f;
    #pragma unroll
    for (int ks = 0; ks < 4; ++ks) {
        int k0 = ks * 32 + quad * 8;
        float4 x0 = *(const float4*)&x[(size_t)row * FIN_ + k0];
        float4 x1 = *(const float4*)&x[(size_t)row * FIN_ + k0 + 4];
        float xs[8] = {x0.x, x0.y, x0.z, x0.w, x1.x, x1.y, x1.z, x1.w};
        short8 v;
        #pragma unroll
        for (int jj = 0; jj < 8; ++jj) {
            v[jj] = f2bf(xs[jj]);
            s1p += xs[jj] * Wa1l[k0 + jj];
            s2p += xs[jj] * Wa2l[k0 + jj];
        }
        fa[ks] = v;
    }
    s1p += __shfl_xor(s1p, 16); s1p += __shfl_xor(s1p, 32);
    s2p += __shfl_xor(s2p, 16); s2p += __shfl_xor(s2p, 32);
    if (wave < 2 && lane < 16) {            // wave 0 -> mt 0 rows, wave 1 -> mt 1 rows
        s1[row0 + wave * 16 + lane] = s1p;
        s2[row0 + wave * 16 + lane] = s2p;
    }

    f32x4 acc[2];
    acc[0] = (f32x4){0.f, 0.f, 0.f, 0.f};
    acc[1] = (f32x4){0.f, 0.f, 0.f, 0.f};
    #pragma unroll
    for (int ks = 0; ks < 4; ++ks) {
        #pragma unroll
        for (int q = 0; q < 2; ++q) {
            short8 fb = *(short8*)&Wb[((ks * 4 + nt0 + q) * 64 + lane) * 8];
            acc[q] = __builtin_amdgcn_mfma_f32_16x16x32_bf16(fa[ks], fb, acc[q], 0, 0, 0);
        }
    }
    #pragma unroll
    for (int q = 0; q < 2; ++q) {
        int o  = (nt0 + q) * 16 + m;
        int ib = ib0 + mt * 16 + quad * 4;
        ushort4 hv;
        hv.x = (unsigned short)f2bf(acc[q][0]);
        hv.y = (unsigned short)f2bf(acc[q][1]);
        hv.z = (unsigned short)f2bf(acc[q][2]);
        hv.w = (unsigned short)f2bf(acc[q][3]);
        *(ushort4*)&hT[(size_t)(b * 64 + o) * N_ + ib] = hv;
    }
}

// ============ kernel 2: attention, BARRIER-FREE K-loop (split-K over waves) ============
// grid = B*(N/16) = 1024 blocks x 256 thr. Wave w owns j-slice ks=w of each 128-tile:
// it computes w(i, j in slice) in regs == the MFMA A-frag for ks=w, loads B-frags for
// nt=0..3 straight from hT (L2), and accumulates partial C over its k-slice. No
// __syncthreads and no LDS in the 16-tile loop; one split-K LDS reduction at the end.
// m_i = lrelu(s1_i + max_j s2_j) upper-bounds every masked score -> no rescaling.
__global__ __launch_bounds__(256) void k_attn(
    const int* __restrict__ adj,
    const unsigned short* __restrict__ hT,
    const float* __restrict__ s1g, const float* __restrict__ s2g,
    const float* __restrict__ gamma, const float* __restrict__ beta,
    float* __restrict__ out)
{
    __shared__ float s2l[N_];              // 8 KB: full-batch s2
    __shared__ float accL[4][16][64];      // 16 KB: [wave][nt*4+reg][lane] split-K partials
    __shared__ float lpw[4][16];           // [wave][i] partial softmax denominators
    __shared__ float red[4];

    const int t = threadIdx.x;
    const int wave = t >> 6, lane = t & 63;
    const int i_ = lane & 15, quad = lane >> 4;
    const int b  = blockIdx.x >> 7;
    const int i0 = (blockIdx.x & 127) * 16;
    const size_t sbase = (size_t)b * N_;
    const size_t hTb   = (size_t)b * 64 * N_;

    // stage full s2 (2048 f32) + per-batch max
    float4 v0 = *(const float4*)&s2g[sbase + 4 * t];
    float4 v1 = *(const float4*)&s2g[sbase + 4 * (t + 256)];
    *(float4*)&s2l[4 * t] = v0;
    *(float4*)&s2l[4 * (t + 256)] = v1;
    float mx = fmaxf(fmaxf(fmaxf(v0.x, v0.y), fmaxf(v0.z, v0.w)),
                     fmaxf(fmaxf(v1.x, v1.y), fmaxf(v1.z, v1.w)));
    #pragma unroll
    for (int d = 32; d; d >>= 1) mx = fmaxf(mx, __shfl_xor(mx, d));
    if (lane == 0) red[wave] = mx;
    __syncthreads();                       // s2l + red visible
    const float smax = fmaxf(fmaxf(red[0], red[1]), fmaxf(red[2], red[3]));
    const float s1v  = s1g[sbase + i0 + i_];          // 16-lane broadcast, L2
    const float mv   = fmaxf(s1v + smax, ALPHA_ * (s1v + smax));

    const int jr = wave * 32 + quad * 8;   // this thread's j-slice (ks = wave)
    const int* adjrow = &adj[(sbase + i0 + i_) * N_ + jr];

    int4 pa0 = *(const int4*)&adjrow[0];   // prefetch adj tile 0
    int4 pa1 = *(const int4*)&adjrow[4];

    f32x4 acc[4];
    #pragma unroll
    for (int nt = 0; nt < 4; ++nt) acc[nt] = (f32x4){0.f, 0.f, 0.f, 0.f};
    float lpart = 0.f;

    for (int tile = 0; tile < 16; ++tile) {
        const int j0 = tile * 128;
        int am[8] = {pa0.x, pa0.y, pa0.z, pa0.w, pa1.x, pa1.y, pa1.z, pa1.w};

        // prefetch next adj tile (wraps on last iter; harmless)
        {
            int jn = ((tile + 1) & 15) * 128;
            pa0 = *(const int4*)&adjrow[jn];
            pa1 = *(const int4*)&adjrow[jn + 4];
        }
        // B-frags for this tile straight from hT (L2-resident, 16B contiguous)
        short8 hv[4];
        #pragma unroll
        for (int nt = 0; nt < 4; ++nt)
            hv[nt] = *(const short8*)&hT[hTb + (size_t)(nt * 16 + i_) * N_ + j0 + jr];

        // w-phase in registers == A-frag for ks=wave
        short8 wv;
        {
            float sum = 0.f;
            #pragma unroll
            for (int jj = 0; jj < 8; ++jj) {
                float ev = s1v + s2l[j0 + jr + jj];
                ev = fmaxf(ev, ALPHA_ * ev);
                float w = (am[jj] > 0) ? __expf(ev - mv) : 0.f;
                short ws = f2bf(w);
                wv[jj] = ws;
                sum += bf2f(ws);           // l consistent with bf16-rounded numerator
            }
            lpart += sum;
        }

        // split-K MFMA: this wave's k-slice, all 4 feature tiles
        #pragma unroll
        for (int nt = 0; nt < 4; ++nt)
            acc[nt] = __builtin_amdgcn_mfma_f32_16x16x32_bf16(wv, hv[nt], acc[nt], 0, 0, 0);
    }

    // denominators: quad-reduce, stash per-wave partial
    lpart += __shfl_xor(lpart, 16);
    lpart += __shfl_xor(lpart, 32);
    if (lane < 16) lpw[wave][lane] = lpart;

    // split-K partials to LDS: element = C_w[i=(lane>>4)*4+reg][o=nt*16+(lane&15)]
    #pragma unroll
    for (int nt = 0; nt < 4; ++nt)
        #pragma unroll
        for (int reg = 0; reg < 4; ++reg)
            accL[wave][nt * 4 + reg][lane] = acc[nt][reg];
    __syncthreads();

    // epilogue: thread (o=lane, i=wave*4+rr); LN over o via wave shuffles
    {
        const int o = lane, ntc = o >> 4, oc = o & 15;
        const float g  = gamma[o];
        const float be = beta[o];
        #pragma unroll
        for (int rr = 0; rr < 4; ++rr) {
            int i = wave * 4 + rr;
            int s = ntc * 4 + (i & 3), lp = (i >> 2) * 16 + oc;
            float c = accL[0][s][lp] + accL[1][s][lp] + accL[2][s][lp] + accL[3][s][lp];
            float l = lpw[0][i] + lpw[1][i] + lpw[2][i] + lpw[3][i];
            float v = c / l;
            float mu = v;
            #pragma unroll
            for (int d = 32; d; d >>= 1) mu += __shfl_xor(mu, d);
            mu *= (1.f / 64.f);
            float dv = v - mu;
            float var = dv * dv;
            #pragma unroll
            for (int d = 32; d; d >>= 1) var += __shfl_xor(var, d);
            var *= (1.f / 64.f);
            float y = dv * rsqrtf(var + LN_EPS_) * g + be;
            out[(sbase + i0 + i) * FOUT_ + o] = y > 0.f ? y : __expf(y) - 1.f;
        }
    }
}

extern "C" void kernel_launch(void* const* d_in, const int* in_sizes, int n_in,
                              void* d_out, int out_size, void* d_ws, size_t ws_size,
                              hipStream_t stream) {
    const float* x     = (const float*)d_in[0];
    const int*   adj   = (const int*)d_in[1];
    const float* W     = (const float*)d_in[2];
    const float* a     = (const float*)d_in[3];
    const float* gamma = (const float*)d_in[4];
    const float* beta  = (const float*)d_in[5];
    float* out = (float*)d_out;

    char* ws = (char*)d_ws;
    unsigned short* hT = (unsigned short*)ws;                      // 2 MB
    float* s1 = (float*)(ws + (size_t)B_ * 64 * N_ * 2);           // 64 KB
    float* s2 = s1 + (size_t)B_ * N_;                              // 64 KB

    k_proj<<<512, 256, 0, stream>>>(x, W, a, hT, s1, s2);
    k_attn<<<B_ * (N_ / 16), 256, 0, stream>>>(adj, hT, s1, s2, gamma, beta, out);
}